// Round 8
// baseline (664.930 us; speedup 1.0000x reference)
//
#include <hip/hip_runtime.h>
#include <cstdint>
#include <cmath>

#define NB 4
#define NQn 128
#define QD 512
#define EMBD 512
#define NH 8
#define DHn 64
#define VOCAB 20000
#define WDn 300
#define VCHUNK 128
#define NCHUNK 157   // ceil(20000/128)
#define RTILE 128    // rows per block in score kernel
#define LSTR 36      // LDS row stride (floats): 144B, 16B-aligned, 2-way banks

typedef float f32x4 __attribute__((ext_vector_type(4)));
typedef float f32x2 __attribute__((ext_vector_type(2)));

__device__ __forceinline__ f32x2 lo2(f32x4 v) { return __builtin_shufflevector(v, v, 0, 1); }
__device__ __forceinline__ f32x2 hi2(f32x4 v) { return __builtin_shufflevector(v, v, 2, 3); }

__device__ __forceinline__ void pk_fma(f32x2 &d, f32x2 a, f32x2 b) {
  asm("v_pk_fma_f32 %0, %1, %2, %0" : "+v"(d) : "v"(a), "v"(b));
}
__device__ __forceinline__ void pk_fma_blo(f32x2 &d, f32x2 a, f32x2 b) {
  asm("v_pk_fma_f32 %0, %1, %2, %0 op_sel:[0,0,0] op_sel_hi:[0,1,1]"
      : "+v"(d) : "v"(a), "v"(b));
}
__device__ __forceinline__ void pk_fma_bhi(f32x2 &d, f32x2 a, f32x2 b) {
  asm("v_pk_fma_f32 %0, %1, %2, %0 op_sel:[1,0,0] op_sel_hi:[1,1,1]"
      : "+v"(d) : "v"(a), "v"(b));
}

__device__ __forceinline__ uint32_t rotl(uint32_t x, int r) {
  return __builtin_amdgcn_alignbit(x, x, 32 - r);
}

// 8 interleaved threefry2x32 chains (key=(0,42)); bits = out0 ^ out1 (verified R1)
#define TFK1 42u
#define TFK2 (0x1BD11BDAu ^ 42u)
__device__ __forceinline__ void tf8(uint32_t (&x0)[8], uint32_t (&x1)[8]) {
#define R8(r) \
  { _Pragma("unroll") for (int j = 0; j < 8; ++j) { x0[j] += x1[j]; x1[j] = rotl(x1[j], r); x1[j] ^= x0[j]; } }
#define K8(a, b) \
  { _Pragma("unroll") for (int j = 0; j < 8; ++j) { x0[j] += (a); x1[j] += (b); } }
  K8(0u, TFK1)
  R8(13) R8(15) R8(26) R8(6)  K8(TFK1, TFK2 + 1u)
  R8(17) R8(29) R8(16) R8(24) K8(TFK2, 0u + 2u)
  R8(13) R8(15) R8(26) R8(6)  K8(0u, TFK1 + 3u)
  R8(17) R8(29) R8(16) R8(24) K8(TFK1, TFK2 + 4u)
  R8(13) R8(15) R8(26) R8(6)  K8(TFK2, 0u + 5u)
#undef R8
#undef K8
}

__device__ __forceinline__ float gumbel_from_bits(uint32_t bits) {
  float f = __uint_as_float((bits >> 9) | 0x3f800000u) - 1.0f;
  float u = fmaxf(f, 1.17549435e-38f);
  float t = __log2f(u);
  float s = __log2f(-t);
  return fmaf(0.69314718f, s, -0.36651292f);
}

// order-isomorphic u64 key: higher val wins; on equal val, LOWER idx wins
__device__ __forceinline__ unsigned long long pack_key(float val, int idx) {
  uint32_t fb = __float_as_uint(val);
  uint32_t key = (fb & 0x80000000u) ? ~fb : (fb | 0x80000000u);
  return ((unsigned long long)key << 32) |
         (unsigned long long)(0xFFFFFFFFu - (uint32_t)idx);
}

// ---------------- K1: LayerNorm + Q projection ----------------
__global__ __launch_bounds__(256, 4) void ln_qproj_kernel(
                                const float* __restrict__ queries,
                                const float* __restrict__ Wq,
                                const float* __restrict__ ln_g,
                                const float* __restrict__ ln_b,
                                float* __restrict__ q_ws) {
  __shared__ float xnT[QD][4];
  const int tid = threadIdx.x;
  const int wave = tid >> 6, lane = tid & 63;
  const int r0 = blockIdx.x * 4;
  const int r = r0 + wave;

  float vals[8];
  float s = 0.f;
#pragma unroll
  for (int j = 0; j < 8; ++j) { vals[j] = queries[r * QD + j * 64 + lane]; s += vals[j]; }
#pragma unroll
  for (int m = 32; m >= 1; m >>= 1) s += __shfl_xor(s, m, 64);
  const float mu = s * (1.f / 512.f);
  float ss = 0.f;
#pragma unroll
  for (int j = 0; j < 8; ++j) { float d = vals[j] - mu; ss += d * d; }
#pragma unroll
  for (int m = 32; m >= 1; m >>= 1) ss += __shfl_xor(ss, m, 64);
  const float rstd = 1.f / sqrtf(ss * (1.f / 512.f) + 1e-5f);
#pragma unroll
  for (int j = 0; j < 8; ++j) {
    int e = j * 64 + lane;
    xnT[e][wave] = (vals[j] - mu) * rstd * ln_g[e] + ln_b[e];
  }
  __syncthreads();

  const int e = blockIdx.y * 256 + tid;
  float a0 = 0.f, a1 = 0.f, a2 = 0.f, a3 = 0.f;
#pragma unroll 4
  for (int i = 0; i < QD; ++i) {
    f32x4 xv = *(const f32x4*)&xnT[i][0];
    float w = Wq[i * EMBD + e];
    a0 += xv.x * w; a1 += xv.y * w; a2 += xv.z * w; a3 += xv.w * w;
  }
  q_ws[(r0 + 0) * EMBD + e] = a0;
  q_ws[(r0 + 1) * EMBD + e] = a1;
  q_ws[(r0 + 2) * EMBD + e] = a2;
  q_ws[(r0 + 3) * EMBD + e] = a3;
}

// ---------------- K2: k = glove @ Wk (bitwise-identical pk path) ----------------
#define BKk 60
__global__ __launch_bounds__(256, 4) void kproj_kernel(
                             const float* __restrict__ glove,
                             const float* __restrict__ Wk,
                             float* __restrict__ k_ws) {
  __shared__ float AsT[BKk][68];
  __shared__ float Bs[BKk][64];
  const int tid = threadIdx.x;
  const int v0 = blockIdx.x * 64, n0 = blockIdx.y * 64;
  const int ty = tid >> 4, tx = tid & 15;
  f32x2 acc2[4][2] = {};
  for (int s = 0; s < 5; ++s) {
    const int w0 = s * BKk;
    __syncthreads();
    for (int f = tid; f < 64 * 15; f += 256) {
      int row = f / 15, c4 = f % 15;
      int v = v0 + row;
      float4 g4 = (v < VOCAB) ? *(const float4*)&glove[(size_t)v * WDn + w0 + c4 * 4]
                              : make_float4(0.f, 0.f, 0.f, 0.f);
      AsT[c4 * 4 + 0][row] = g4.x;
      AsT[c4 * 4 + 1][row] = g4.y;
      AsT[c4 * 4 + 2][row] = g4.z;
      AsT[c4 * 4 + 3][row] = g4.w;
    }
    for (int f = tid; f < BKk * 16; f += 256) {
      int row = f / 16, c4 = f % 16;
      *(float4*)&Bs[row][c4 * 4] = *(const float4*)&Wk[(size_t)(w0 + row) * EMBD + n0 + c4 * 4];
    }
    __syncthreads();
#pragma unroll 4
    for (int w = 0; w < BKk; ++w) {
      f32x4 aq = *(const f32x4*)&AsT[w][ty * 4];
      f32x4 bv = *(const f32x4*)&Bs[w][tx * 4];
      f32x2 bl = lo2(bv), bh = hi2(bv);
      f32x2 a01 = lo2(aq), a23 = hi2(aq);
      pk_fma_blo(acc2[0][0], a01, bl); pk_fma_blo(acc2[0][1], a01, bh);
      pk_fma_bhi(acc2[1][0], a01, bl); pk_fma_bhi(acc2[1][1], a01, bh);
      pk_fma_blo(acc2[2][0], a23, bl); pk_fma_blo(acc2[2][1], a23, bh);
      pk_fma_bhi(acc2[3][0], a23, bl); pk_fma_bhi(acc2[3][1], a23, bh);
    }
  }
#pragma unroll
  for (int i = 0; i < 4; ++i) {
    int v = v0 + ty * 4 + i;
    if (v < VOCAB) {
      float4 st = make_float4(acc2[i][0].x, acc2[i][0].y, acc2[i][1].x, acc2[i][1].y);
      *(float4*)&k_ws[(size_t)v * EMBD + n0 + tx * 4] = st;
    }
  }
}

// ---------------- K3: 128x128 tile, 8x8/thread, d staged in two halves ----------------
template<bool FULL>
__device__ __forceinline__ void score_epi(const f32x2 (&acc)[8][8],
                                          int v0, int tx, int ty, int rowtile, int h,
                                          unsigned long long* __restrict__ pk_buf) {
#pragma unroll
  for (int i = 0; i < 8; ++i) {
    const int r = rowtile * RTILE + ty * 8 + i;   // 0..511 within head
    const int b = r >> 7, q = r & 127;
    const int rowidx = (b * NH + h) * NQn + q;
    const uint32_t base = (uint32_t)rowidx * (uint32_t)VOCAB;

    uint32_t x0[8], x1[8];
#pragma unroll
    for (int j = 0; j < 8; ++j) {
      x0[j] = 0u;
      x1[j] = base + (uint32_t)(v0 + tx + 16 * j);
    }
    tf8(x0, x1);

    float best = -INFINITY; int bidx = 0x7fffffff;
#pragma unroll
    for (int j = 0; j < 8; ++j) {
      int v = v0 + tx + 16 * j;
      if (FULL || v < VOCAB) {
        float g = gumbel_from_bits(x0[j] ^ x1[j]);
        float val = (acc[i][j].x + acc[i][j].y) - g;  // q pre-scaled by 0.125
        if (val > best) { best = val; bidx = v; }     // v increasing -> lowest-idx ties
      }
    }
#pragma unroll
    for (int m = 8; m >= 1; m >>= 1) {
      float ov = __shfl_xor(best, m, 64);
      int   oi = __shfl_xor(bidx, m, 64);
      if (ov > best || (ov == best && oi < bidx)) { best = ov; bidx = oi; }
    }
    if (tx == 0) atomicMax(&pk_buf[rowidx], pack_key(best, bidx));
  }
}

__global__ __launch_bounds__(256, 2) void score_kernel(
                             const float* __restrict__ q_ws,
                             const float* __restrict__ k_ws,
                             unsigned long long* __restrict__ pk_buf) {
  __shared__ float Qs[RTILE][LSTR];   // 18432 B
  __shared__ float Ks[RTILE][LSTR];   // 18432 B
  const int tid = threadIdx.x;
  const int chunk = blockIdx.x, rowtile = blockIdx.y, h = blockIdx.z;
  const int v0 = chunk * VCHUNK;
  const int ty = tid >> 4, tx = tid & 15;
  const int rowbase = rowtile * RTILE;   // within-head row offset (head-local 0..511)

  f32x2 acc[8][8] = {};

#pragma unroll
  for (int half = 0; half < 2; ++half) {
    const int D0 = half * 32;
    __syncthreads();
    // stage Q half: 128 rows x 32 dims
    for (int f = tid; f < RTILE * 8; f += 256) {
      int row = f >> 3, c4 = f & 7;
      f32x4 qv = *(const f32x4*)&q_ws[(size_t)(rowbase + row) * EMBD + h * DHn + D0 + c4 * 4];
      qv *= 0.125f;                                  // fold scale (2^-3, exact)
      *(f32x4*)&Qs[row][c4 * 4] = qv;
    }
    // stage K half: 128 cols x 32 dims
    for (int f = tid; f < RTILE * 8; f += 256) {
      int col = f >> 3, c4 = f & 7;
      int v = v0 + col;
      f32x4 k4 = {0.f, 0.f, 0.f, 0.f};
      if (v < VOCAB) k4 = *(const f32x4*)&k_ws[(size_t)v * EMBD + h * DHn + D0 + c4 * 4];
      *(f32x4*)&Ks[col][c4 * 4] = k4;
    }
    __syncthreads();

#pragma unroll 2
    for (int d0 = 0; d0 < 32; d0 += 4) {
      f32x4 kv[8], qv[8];
#pragma unroll
      for (int j = 0; j < 8; ++j) kv[j] = *(const f32x4*)&Ks[tx + 16 * j][d0];
#pragma unroll
      for (int i = 0; i < 8; ++i) qv[i] = *(const f32x4*)&Qs[ty * 8 + i][d0];
#pragma unroll
      for (int i = 0; i < 8; ++i) {
        f32x2 ql = lo2(qv[i]), qh = hi2(qv[i]);
#pragma unroll
        for (int j = 0; j < 8; ++j) {
          pk_fma(acc[i][j], ql, lo2(kv[j]));
          pk_fma(acc[i][j], qh, hi2(kv[j]));
        }
      }
    }
  }

  if (v0 + VCHUNK <= VOCAB)
    score_epi<true>(acc, v0, tx, ty, rowtile, h, pk_buf);
  else
    score_epi<false>(acc, v0, tx, ty, rowtile, h, pk_buf);
}

// ---------------- K5: gather + V projection + out proj + residual ----------------
__global__ __launch_bounds__(256, 4) void out_kernel(
                           const float* __restrict__ queries,
                           const float* __restrict__ glove,
                           const float* __restrict__ Wv,
                           const float* __restrict__ Wout,
                           const float* __restrict__ b_out,
                           const unsigned long long* __restrict__ pk_buf,
                           float* __restrict__ out) {
  __shared__ float gl[4][NH][WDn];
  __shared__ float vrow[4][EMBD];
  __shared__ int idxs[4][NH];
  const int tid = threadIdx.x;
  const int r0 = blockIdx.x * 4;
  if (tid < 32) {
    int rr = tid >> 3, hh = tid & 7;
    int r = r0 + rr, b = r >> 7, q = r & 127;
    unsigned long long p = pk_buf[(b * NH + hh) * NQn + q];
    idxs[rr][hh] = (int)(0xFFFFFFFFu - (uint32_t)(p & 0xFFFFFFFFull));
  }
  __syncthreads();
  for (int f = tid; f < 32 * 75; f += 256) {
    int rp = f / 75, c4 = f % 75;
    int rr = rp >> 3, hh = rp & 7;
    *(float4*)&gl[rr][hh][c4 * 4] = *(const float4*)&glove[(size_t)idxs[rr][hh] * WDn + c4 * 4];
  }
  __syncthreads();
  for (int e = tid; e < EMBD; e += 256) {
    float a0 = 0.f, a1 = 0.f, a2 = 0.f, a3 = 0.f;
    int hh = e >> 6;
    for (int w = 0; w < WDn; ++w) {
      float wv = Wv[(size_t)w * EMBD + e];
      a0 += gl[0][hh][w] * wv; a1 += gl[1][hh][w] * wv;
      a2 += gl[2][hh][w] * wv; a3 += gl[3][hh][w] * wv;
    }
    vrow[0][e] = a0; vrow[1][e] = a1; vrow[2][e] = a2; vrow[3][e] = a3;
  }
  __syncthreads();
  for (int j = tid; j < EMBD; j += 256) {
    float a0 = 0.f, a1 = 0.f, a2 = 0.f, a3 = 0.f;
    for (int e = 0; e < EMBD; ++e) {
      float wo = Wout[(size_t)e * QD + j];
      a0 += vrow[0][e] * wo; a1 += vrow[1][e] * wo;
      a2 += vrow[2][e] * wo; a3 += vrow[3][e] * wo;
    }
    float bb = b_out[j];
    out[(size_t)(r0 + 0) * QD + j] = queries[(size_t)(r0 + 0) * QD + j] + a0 + bb;
    out[(size_t)(r0 + 1) * QD + j] = queries[(size_t)(r0 + 1) * QD + j] + a1 + bb;
    out[(size_t)(r0 + 2) * QD + j] = queries[(size_t)(r0 + 2) * QD + j] + a2 + bb;
    out[(size_t)(r0 + 3) * QD + j] = queries[(size_t)(r0 + 3) * QD + j] + a3 + bb;
  }
}

extern "C" void kernel_launch(void* const* d_in, const int* in_sizes, int n_in,
                              void* d_out, int out_size, void* d_ws, size_t ws_size,
                              hipStream_t stream) {
  const float* queries = (const float*)d_in[0];
  const float* glove   = (const float*)d_in[1];
  const float* Wq      = (const float*)d_in[2];
  const float* Wk      = (const float*)d_in[3];
  const float* Wv      = (const float*)d_in[4];
  const float* Wout    = (const float*)d_in[5];
  const float* b_out   = (const float*)d_in[6];
  const float* ln_g    = (const float*)d_in[7];
  const float* ln_b    = (const float*)d_in[8];
  float* out = (float*)d_out;

  float* ws   = (float*)d_ws;
  float* q_ws = ws;
  float* k_ws = q_ws + (size_t)NB * NQn * EMBD;
  unsigned long long* pk_buf =
      (unsigned long long*)(k_ws + (size_t)VOCAB * EMBD);

  hipMemsetAsync(pk_buf, 0, (size_t)NB * NH * NQn * sizeof(unsigned long long), stream);

  hipLaunchKernelGGL(ln_qproj_kernel, dim3(128, 2), dim3(256), 0, stream,
                     queries, Wq, ln_g, ln_b, q_ws);
  hipLaunchKernelGGL(kproj_kernel, dim3(313, 8), dim3(256), 0, stream,
                     glove, Wk, k_ws);
  hipLaunchKernelGGL(score_kernel, dim3(NCHUNK, 4, NH), dim3(256), 0, stream,
                     q_ws, k_ws, pk_buf);
  hipLaunchKernelGGL(out_kernel, dim3(128), dim3(256), 0, stream,
                     queries, glove, Wv, Wout, b_out, pk_buf, out);
}

// Round 9
// 535.816 us; speedup vs baseline: 1.2410x; 1.2410x over previous
//
#include <hip/hip_runtime.h>
#include <cstdint>
#include <cmath>

#define NB 4
#define NQn 128
#define QD 512
#define EMBD 512
#define NH 8
#define DHn 64
#define VOCAB 20000
#define WDn 300
#define VCHUNK 128
#define NCHUNK 157   // ceil(20000/128)
// chunk-range split for the A/B/C score variants
#define CH_A 53
#define CH_B 53
#define CH_C 51

typedef float f32x4 __attribute__((ext_vector_type(4)));
typedef float f32x2 __attribute__((ext_vector_type(2)));

__device__ __forceinline__ f32x2 lo2(f32x4 v) { return __builtin_shufflevector(v, v, 0, 1); }
__device__ __forceinline__ f32x2 hi2(f32x4 v) { return __builtin_shufflevector(v, v, 2, 3); }

__device__ __forceinline__ void pk_fma(f32x2 &d, f32x2 a, f32x2 b) {
  asm("v_pk_fma_f32 %0, %1, %2, %0" : "+v"(d) : "v"(a), "v"(b));
}
__device__ __forceinline__ void pk_fma_blo(f32x2 &d, f32x2 a, f32x2 b) {
  asm("v_pk_fma_f32 %0, %1, %2, %0 op_sel:[0,0,0] op_sel_hi:[0,1,1]"
      : "+v"(d) : "v"(a), "v"(b));
}
__device__ __forceinline__ void pk_fma_bhi(f32x2 &d, f32x2 a, f32x2 b) {
  asm("v_pk_fma_f32 %0, %1, %2, %0 op_sel:[1,0,0] op_sel_hi:[1,1,1]"
      : "+v"(d) : "v"(a), "v"(b));
}

__device__ __forceinline__ uint32_t rotl(uint32_t x, int r) {
  return __builtin_amdgcn_alignbit(x, x, 32 - r);
}

// N interleaved threefry2x32 chains (key=(0,42)); bits = out0 ^ out1 (verified R1)
#define TFK1 42u
#define TFK2 (0x1BD11BDAu ^ 42u)
template<int N>
__device__ __forceinline__ void tfn(uint32_t (&x0)[N], uint32_t (&x1)[N]) {
#define RN(r) \
  { _Pragma("unroll") for (int j = 0; j < N; ++j) { x0[j] += x1[j]; x1[j] = rotl(x1[j], r); x1[j] ^= x0[j]; } }
#define KN(a, b) \
  { _Pragma("unroll") for (int j = 0; j < N; ++j) { x0[j] += (a); x1[j] += (b); } }
  KN(0u, TFK1)
  RN(13) RN(15) RN(26) RN(6)  KN(TFK1, TFK2 + 1u)
  RN(17) RN(29) RN(16) RN(24) KN(TFK2, 0u + 2u)
  RN(13) RN(15) RN(26) RN(6)  KN(0u, TFK1 + 3u)
  RN(17) RN(29) RN(16) RN(24) KN(TFK1, TFK2 + 4u)
  RN(13) RN(15) RN(26) RN(6)  KN(TFK2, 0u + 5u)
#undef RN
#undef KN
}

__device__ __forceinline__ float gumbel_from_bits(uint32_t bits) {
  float f = __uint_as_float((bits >> 9) | 0x3f800000u) - 1.0f;
  float u = fmaxf(f, 1.17549435e-38f);
  float t = __log2f(u);
  float s = __log2f(-t);
  return fmaf(0.69314718f, s, -0.36651292f);
}

// order-isomorphic u64 key: higher val wins; on equal val, LOWER idx wins
__device__ __forceinline__ unsigned long long pack_key(float val, int idx) {
  uint32_t fb = __float_as_uint(val);
  uint32_t key = (fb & 0x80000000u) ? ~fb : (fb | 0x80000000u);
  return ((unsigned long long)key << 32) |
         (unsigned long long)(0xFFFFFFFFu - (uint32_t)idx);
}

// ---------------- K1: LayerNorm + Q projection ----------------
__global__ __launch_bounds__(256, 4) void ln_qproj_kernel(
                                const float* __restrict__ queries,
                                const float* __restrict__ Wq,
                                const float* __restrict__ ln_g,
                                const float* __restrict__ ln_b,
                                float* __restrict__ q_ws) {
  __shared__ float xnT[QD][4];
  const int tid = threadIdx.x;
  const int wave = tid >> 6, lane = tid & 63;
  const int r0 = blockIdx.x * 4;
  const int r = r0 + wave;

  float vals[8];
  float s = 0.f;
#pragma unroll
  for (int j = 0; j < 8; ++j) { vals[j] = queries[r * QD + j * 64 + lane]; s += vals[j]; }
#pragma unroll
  for (int m = 32; m >= 1; m >>= 1) s += __shfl_xor(s, m, 64);
  const float mu = s * (1.f / 512.f);
  float ss = 0.f;
#pragma unroll
  for (int j = 0; j < 8; ++j) { float d = vals[j] - mu; ss += d * d; }
#pragma unroll
  for (int m = 32; m >= 1; m >>= 1) ss += __shfl_xor(ss, m, 64);
  const float rstd = 1.f / sqrtf(ss * (1.f / 512.f) + 1e-5f);
#pragma unroll
  for (int j = 0; j < 8; ++j) {
    int e = j * 64 + lane;
    xnT[e][wave] = (vals[j] - mu) * rstd * ln_g[e] + ln_b[e];
  }
  __syncthreads();

  const int e = blockIdx.y * 256 + tid;
  float a0 = 0.f, a1 = 0.f, a2 = 0.f, a3 = 0.f;
#pragma unroll 4
  for (int i = 0; i < QD; ++i) {
    f32x4 xv = *(const f32x4*)&xnT[i][0];
    float w = Wq[i * EMBD + e];
    a0 += xv.x * w; a1 += xv.y * w; a2 += xv.z * w; a3 += xv.w * w;
  }
  q_ws[(r0 + 0) * EMBD + e] = a0;
  q_ws[(r0 + 1) * EMBD + e] = a1;
  q_ws[(r0 + 2) * EMBD + e] = a2;
  q_ws[(r0 + 3) * EMBD + e] = a3;
}

// ---------------- K2: k = glove @ Wk (bitwise-identical pk path) ----------------
#define BKk 60
__global__ __launch_bounds__(256, 4) void kproj_kernel(
                             const float* __restrict__ glove,
                             const float* __restrict__ Wk,
                             float* __restrict__ k_ws) {
  __shared__ float AsT[BKk][68];
  __shared__ float Bs[BKk][64];
  const int tid = threadIdx.x;
  const int v0 = blockIdx.x * 64, n0 = blockIdx.y * 64;
  const int ty = tid >> 4, tx = tid & 15;
  f32x2 acc2[4][2] = {};
  for (int s = 0; s < 5; ++s) {
    const int w0 = s * BKk;
    __syncthreads();
    for (int f = tid; f < 64 * 15; f += 256) {
      int row = f / 15, c4 = f % 15;
      int v = v0 + row;
      float4 g4 = (v < VOCAB) ? *(const float4*)&glove[(size_t)v * WDn + w0 + c4 * 4]
                              : make_float4(0.f, 0.f, 0.f, 0.f);
      AsT[c4 * 4 + 0][row] = g4.x;
      AsT[c4 * 4 + 1][row] = g4.y;
      AsT[c4 * 4 + 2][row] = g4.z;
      AsT[c4 * 4 + 3][row] = g4.w;
    }
    for (int f = tid; f < BKk * 16; f += 256) {
      int row = f / 16, c4 = f % 16;
      *(float4*)&Bs[row][c4 * 4] = *(const float4*)&Wk[(size_t)(w0 + row) * EMBD + n0 + c4 * 4];
    }
    __syncthreads();
#pragma unroll 4
    for (int w = 0; w < BKk; ++w) {
      f32x4 aq = *(const f32x4*)&AsT[w][ty * 4];
      f32x4 bv = *(const f32x4*)&Bs[w][tx * 4];
      f32x2 bl = lo2(bv), bh = hi2(bv);
      f32x2 a01 = lo2(aq), a23 = hi2(aq);
      pk_fma_blo(acc2[0][0], a01, bl); pk_fma_blo(acc2[0][1], a01, bh);
      pk_fma_bhi(acc2[1][0], a01, bl); pk_fma_bhi(acc2[1][1], a01, bh);
      pk_fma_blo(acc2[2][0], a23, bl); pk_fma_blo(acc2[2][1], a23, bh);
      pk_fma_bhi(acc2[3][0], a23, bl); pk_fma_bhi(acc2[3][1], a23, bh);
    }
  }
#pragma unroll
  for (int i = 0; i < 4; ++i) {
    int v = v0 + ty * 4 + i;
    if (v < VOCAB) {
      float4 st = make_float4(acc2[i][0].x, acc2[i][0].y, acc2[i][1].x, acc2[i][1].y);
      *(float4*)&k_ws[(size_t)v * EMBD + n0 + tx * 4] = st;
    }
  }
}

// ---------------- K3: score (A/B/C ablation variants over chunk ranges) ----------------
// Epilogue EPI=0: one row at a time, tf8. EPI=1: two rows jointly, tf16.
template<int EPI, bool FULL>
__device__ __forceinline__ void score_epi(const f32x2 (&acc)[4][8],
                                          int v0, int tx, int ty, int rowtile, int h,
                                          unsigned long long* __restrict__ pk_buf) {
  if (EPI == 0) {
#pragma unroll
    for (int i = 0; i < 4; ++i) {
      const int r = rowtile * 64 + ty * 4 + i;
      const int b = r >> 7, q = r & 127;
      const int rowidx = (b * NH + h) * NQn + q;
      const uint32_t base = (uint32_t)rowidx * (uint32_t)VOCAB;
      uint32_t x0[8], x1[8];
#pragma unroll
      for (int j = 0; j < 8; ++j) { x0[j] = 0u; x1[j] = base + (uint32_t)(v0 + tx + 16 * j); }
      tfn<8>(x0, x1);
      float best = -INFINITY; int bidx = 0x7fffffff;
#pragma unroll
      for (int j = 0; j < 8; ++j) {
        int v = v0 + tx + 16 * j;
        if (FULL || v < VOCAB) {
          float g = gumbel_from_bits(x0[j] ^ x1[j]);
          float val = (acc[i][j].x + acc[i][j].y) - g;
          if (val > best) { best = val; bidx = v; }
        }
      }
#pragma unroll
      for (int m = 8; m >= 1; m >>= 1) {
        float ov = __shfl_xor(best, m, 64);
        int   oi = __shfl_xor(bidx, m, 64);
        if (ov > best || (ov == best && oi < bidx)) { best = ov; bidx = oi; }
      }
      if (tx == 0) atomicMax(&pk_buf[rowidx], pack_key(best, bidx));
    }
  } else {
#pragma unroll
    for (int ip = 0; ip < 4; ip += 2) {
      uint32_t x0[16], x1[16];
#pragma unroll
      for (int ii = 0; ii < 2; ++ii) {
        const int r = rowtile * 64 + ty * 4 + ip + ii;
        const int b = r >> 7, q = r & 127;
        const uint32_t base = (uint32_t)((b * NH + h) * NQn + q) * (uint32_t)VOCAB;
#pragma unroll
        for (int j = 0; j < 8; ++j) {
          x0[ii * 8 + j] = 0u;
          x1[ii * 8 + j] = base + (uint32_t)(v0 + tx + 16 * j);
        }
      }
      tfn<16>(x0, x1);
#pragma unroll
      for (int ii = 0; ii < 2; ++ii) {
        const int i = ip + ii;
        const int r = rowtile * 64 + ty * 4 + i;
        const int b = r >> 7, q = r & 127;
        const int rowidx = (b * NH + h) * NQn + q;
        float best = -INFINITY; int bidx = 0x7fffffff;
#pragma unroll
        for (int j = 0; j < 8; ++j) {
          int v = v0 + tx + 16 * j;
          if (FULL || v < VOCAB) {
            float g = gumbel_from_bits(x0[ii * 8 + j] ^ x1[ii * 8 + j]);
            float val = (acc[i][j].x + acc[i][j].y) - g;
            if (val > best) { best = val; bidx = v; }
          }
        }
#pragma unroll
        for (int m = 8; m >= 1; m >>= 1) {
          float ov = __shfl_xor(best, m, 64);
          int   oi = __shfl_xor(bidx, m, 64);
          if (ov > best || (ov == best && oi < bidx)) { best = ov; bidx = oi; }
        }
        if (tx == 0) atomicMax(&pk_buf[rowidx], pack_key(best, bidx));
      }
    }
  }
}

// DOT=0: inline-asm v_pk_fma_f32. DOT=1: __builtin_elementwise_fma (compiler-scheduled,
// identical per-accumulator order -> bitwise-identical results).
template<int DOT, int EPI>
__device__ __forceinline__ void score_body(const float* __restrict__ q_ws,
                                           const float* __restrict__ k_ws,
                                           unsigned long long* __restrict__ pk_buf,
                                           int chunk) {
  __shared__ float Qs[64 * 68];
  __shared__ float Ks[128 * 68];
  const int tid = threadIdx.x;
  const int rowtile = blockIdx.y, h = blockIdx.z;
  const int v0 = chunk * VCHUNK;
  const int ty = tid >> 4, tx = tid & 15;

  for (int f = tid; f < 64 * 16; f += 256) {
    int row = f >> 4, c4 = f & 15;
    f32x4 qv = *(const f32x4*)&q_ws[(size_t)(rowtile * 64 + row) * EMBD + h * DHn + c4 * 4];
    qv *= 0.125f;
    *(f32x4*)&Qs[row * 68 + c4 * 4] = qv;
  }
  for (int f = tid; f < 128 * 16; f += 256) {
    int row = f >> 4, c4 = f & 15;
    int v = v0 + row;
    f32x4 k4 = {0.f, 0.f, 0.f, 0.f};
    if (v < VOCAB) k4 = *(const f32x4*)&k_ws[(size_t)v * EMBD + h * DHn + c4 * 4];
    *(f32x4*)&Ks[row * 68 + c4 * 4] = k4;
  }
  __syncthreads();

  f32x2 acc[4][8] = {};
#pragma unroll 1
  for (int d0 = 0; d0 < DHn; d0 += 4) {
    const float* kb = &Ks[tx * 68 + d0];
    f32x4 k0 = *(const f32x4*)(kb + 0 * 16 * 68);
    f32x4 k1 = *(const f32x4*)(kb + 1 * 16 * 68);
    f32x4 k2 = *(const f32x4*)(kb + 2 * 16 * 68);
    f32x4 k3 = *(const f32x4*)(kb + 3 * 16 * 68);
    f32x4 k4 = *(const f32x4*)(kb + 4 * 16 * 68);
    f32x4 k5 = *(const f32x4*)(kb + 5 * 16 * 68);
    f32x4 k6 = *(const f32x4*)(kb + 6 * 16 * 68);
    f32x4 k7 = *(const f32x4*)(kb + 7 * 16 * 68);
#pragma unroll
    for (int i = 0; i < 4; ++i) {
      f32x4 qv = *(const f32x4*)&Qs[(ty * 4 + i) * 68 + d0];
      f32x2 ql = lo2(qv), qh = hi2(qv);
      if (DOT == 0) {
        pk_fma(acc[i][0], ql, lo2(k0)); pk_fma(acc[i][0], qh, hi2(k0));
        pk_fma(acc[i][1], ql, lo2(k1)); pk_fma(acc[i][1], qh, hi2(k1));
        pk_fma(acc[i][2], ql, lo2(k2)); pk_fma(acc[i][2], qh, hi2(k2));
        pk_fma(acc[i][3], ql, lo2(k3)); pk_fma(acc[i][3], qh, hi2(k3));
        pk_fma(acc[i][4], ql, lo2(k4)); pk_fma(acc[i][4], qh, hi2(k4));
        pk_fma(acc[i][5], ql, lo2(k5)); pk_fma(acc[i][5], qh, hi2(k5));
        pk_fma(acc[i][6], ql, lo2(k6)); pk_fma(acc[i][6], qh, hi2(k6));
        pk_fma(acc[i][7], ql, lo2(k7)); pk_fma(acc[i][7], qh, hi2(k7));
      } else {
        acc[i][0] = __builtin_elementwise_fma(ql, lo2(k0), acc[i][0]);
        acc[i][0] = __builtin_elementwise_fma(qh, hi2(k0), acc[i][0]);
        acc[i][1] = __builtin_elementwise_fma(ql, lo2(k1), acc[i][1]);
        acc[i][1] = __builtin_elementwise_fma(qh, hi2(k1), acc[i][1]);
        acc[i][2] = __builtin_elementwise_fma(ql, lo2(k2), acc[i][2]);
        acc[i][2] = __builtin_elementwise_fma(qh, hi2(k2), acc[i][2]);
        acc[i][3] = __builtin_elementwise_fma(ql, lo2(k3), acc[i][3]);
        acc[i][3] = __builtin_elementwise_fma(qh, hi2(k3), acc[i][3]);
        acc[i][4] = __builtin_elementwise_fma(ql, lo2(k4), acc[i][4]);
        acc[i][4] = __builtin_elementwise_fma(qh, hi2(k4), acc[i][4]);
        acc[i][5] = __builtin_elementwise_fma(ql, lo2(k5), acc[i][5]);
        acc[i][5] = __builtin_elementwise_fma(qh, hi2(k5), acc[i][5]);
        acc[i][6] = __builtin_elementwise_fma(ql, lo2(k6), acc[i][6]);
        acc[i][6] = __builtin_elementwise_fma(qh, hi2(k6), acc[i][6]);
        acc[i][7] = __builtin_elementwise_fma(ql, lo2(k7), acc[i][7]);
        acc[i][7] = __builtin_elementwise_fma(qh, hi2(k7), acc[i][7]);
      }
    }
  }

  if (v0 + VCHUNK <= VOCAB)
    score_epi<EPI, true>(acc, v0, tx, ty, rowtile, h, pk_buf);
  else
    score_epi<EPI, false>(acc, v0, tx, ty, rowtile, h, pk_buf);
}

__global__ __launch_bounds__(256, 3) void score_A(
    const float* __restrict__ q_ws, const float* __restrict__ k_ws,
    unsigned long long* __restrict__ pk_buf) {
  score_body<0, 0>(q_ws, k_ws, pk_buf, blockIdx.x);
}
__global__ __launch_bounds__(256, 3) void score_B(
    const float* __restrict__ q_ws, const float* __restrict__ k_ws,
    unsigned long long* __restrict__ pk_buf) {
  score_body<1, 0>(q_ws, k_ws, pk_buf, blockIdx.x + CH_A);
}
__global__ __launch_bounds__(256, 3) void score_C(
    const float* __restrict__ q_ws, const float* __restrict__ k_ws,
    unsigned long long* __restrict__ pk_buf) {
  score_body<0, 1>(q_ws, k_ws, pk_buf, blockIdx.x + CH_A + CH_B);
}

// ---------------- K5: gather + V projection + out proj + residual ----------------
__global__ __launch_bounds__(256, 4) void out_kernel(
                           const float* __restrict__ queries,
                           const float* __restrict__ glove,
                           const float* __restrict__ Wv,
                           const float* __restrict__ Wout,
                           const float* __restrict__ b_out,
                           const unsigned long long* __restrict__ pk_buf,
                           float* __restrict__ out) {
  __shared__ float gl[4][NH][WDn];
  __shared__ float vrow[4][EMBD];
  __shared__ int idxs[4][NH];
  const int tid = threadIdx.x;
  const int r0 = blockIdx.x * 4;
  if (tid < 32) {
    int rr = tid >> 3, hh = tid & 7;
    int r = r0 + rr, b = r >> 7, q = r & 127;
    unsigned long long p = pk_buf[(b * NH + hh) * NQn + q];
    idxs[rr][hh] = (int)(0xFFFFFFFFu - (uint32_t)(p & 0xFFFFFFFFull));
  }
  __syncthreads();
  for (int f = tid; f < 32 * 75; f += 256) {
    int rp = f / 75, c4 = f % 75;
    int rr = rp >> 3, hh = rp & 7;
    *(float4*)&gl[rr][hh][c4 * 4] = *(const float4*)&glove[(size_t)idxs[rr][hh] * WDn + c4 * 4];
  }
  __syncthreads();
  for (int e = tid; e < EMBD; e += 256) {
    float a0 = 0.f, a1 = 0.f, a2 = 0.f, a3 = 0.f;
    int hh = e >> 6;
    for (int w = 0; w < WDn; ++w) {
      float wv = Wv[(size_t)w * EMBD + e];
      a0 += gl[0][hh][w] * wv; a1 += gl[1][hh][w] * wv;
      a2 += gl[2][hh][w] * wv; a3 += gl[3][hh][w] * wv;
    }
    vrow[0][e] = a0; vrow[1][e] = a1; vrow[2][e] = a2; vrow[3][e] = a3;
  }
  __syncthreads();
  for (int j = tid; j < EMBD; j += 256) {
    float a0 = 0.f, a1 = 0.f, a2 = 0.f, a3 = 0.f;
    for (int e = 0; e < EMBD; ++e) {
      float wo = Wout[(size_t)e * QD + j];
      a0 += vrow[0][e] * wo; a1 += vrow[1][e] * wo;
      a2 += vrow[2][e] * wo; a3 += vrow[3][e] * wo;
    }
    float bb = b_out[j];
    out[(size_t)(r0 + 0) * QD + j] = queries[(size_t)(r0 + 0) * QD + j] + a0 + bb;
    out[(size_t)(r0 + 1) * QD + j] = queries[(size_t)(r0 + 1) * QD + j] + a1 + bb;
    out[(size_t)(r0 + 2) * QD + j] = queries[(size_t)(r0 + 2) * QD + j] + a2 + bb;
    out[(size_t)(r0 + 3) * QD + j] = queries[(size_t)(r0 + 3) * QD + j] + a3 + bb;
  }
}

extern "C" void kernel_launch(void* const* d_in, const int* in_sizes, int n_in,
                              void* d_out, int out_size, void* d_ws, size_t ws_size,
                              hipStream_t stream) {
  const float* queries = (const float*)d_in[0];
  const float* glove   = (const float*)d_in[1];
  const float* Wq      = (const float*)d_in[2];
  const float* Wk      = (const float*)d_in[3];
  const float* Wv      = (const float*)d_in[4];
  const float* Wout    = (const float*)d_in[5];
  const float* b_out   = (const float*)d_in[6];
  const float* ln_g    = (const float*)d_in[7];
  const float* ln_b    = (const float*)d_in[8];
  float* out = (float*)d_out;

  float* ws   = (float*)d_ws;
  float* q_ws = ws;
  float* k_ws = q_ws + (size_t)NB * NQn * EMBD;
  unsigned long long* pk_buf =
      (unsigned long long*)(k_ws + (size_t)VOCAB * EMBD);

  hipMemsetAsync(pk_buf, 0, (size_t)NB * NH * NQn * sizeof(unsigned long long), stream);

  hipLaunchKernelGGL(ln_qproj_kernel, dim3(128, 2), dim3(256), 0, stream,
                     queries, Wq, ln_g, ln_b, q_ws);
  hipLaunchKernelGGL(kproj_kernel, dim3(313, 8), dim3(256), 0, stream,
                     glove, Wk, k_ws);
  hipLaunchKernelGGL(score_A, dim3(CH_A, 8, NH), dim3(256), 0, stream,
                     q_ws, k_ws, pk_buf);
  hipLaunchKernelGGL(score_B, dim3(CH_B, 8, NH), dim3(256), 0, stream,
                     q_ws, k_ws, pk_buf);
  hipLaunchKernelGGL(score_C, dim3(CH_C, 8, NH), dim3(256), 0, stream,
                     q_ws, k_ws, pk_buf);
  hipLaunchKernelGGL(out_kernel, dim3(128), dim3(256), 0, stream,
                     queries, glove, Wv, Wout, b_out, pk_buf, out);
}

// Round 10
// 535.505 us; speedup vs baseline: 1.2417x; 1.0006x over previous
//
#include <hip/hip_runtime.h>
#include <cstdint>
#include <cmath>

#define NB 4
#define NQn 128
#define QD 512
#define EMBD 512
#define NH 8
#define DHn 64
#define VOCAB 20000
#define WDn 300
#define VCHUNK 128
#define NCHUNK 157   // ceil(20000/128)

typedef float f32x4 __attribute__((ext_vector_type(4)));
typedef float f32x2 __attribute__((ext_vector_type(2)));

__device__ __forceinline__ f32x2 lo2(f32x4 v) { return __builtin_shufflevector(v, v, 0, 1); }
__device__ __forceinline__ f32x2 hi2(f32x4 v) { return __builtin_shufflevector(v, v, 2, 3); }

__device__ __forceinline__ void pk_fma(f32x2 &d, f32x2 a, f32x2 b) {
  asm("v_pk_fma_f32 %0, %1, %2, %0" : "+v"(d) : "v"(a), "v"(b));
}
__device__ __forceinline__ void pk_fma_blo(f32x2 &d, f32x2 a, f32x2 b) {
  asm("v_pk_fma_f32 %0, %1, %2, %0 op_sel:[0,0,0] op_sel_hi:[0,1,1]"
      : "+v"(d) : "v"(a), "v"(b));
}
__device__ __forceinline__ void pk_fma_bhi(f32x2 &d, f32x2 a, f32x2 b) {
  asm("v_pk_fma_f32 %0, %1, %2, %0 op_sel:[1,0,0] op_sel_hi:[1,1,1]"
      : "+v"(d) : "v"(a), "v"(b));
}

__device__ __forceinline__ uint32_t rotl(uint32_t x, int r) {
  return __builtin_amdgcn_alignbit(x, x, 32 - r);
}

// 8 interleaved threefry2x32 chains (key=(0,42)); bits = out0 ^ out1 (verified R1)
#define TFK1 42u
#define TFK2 (0x1BD11BDAu ^ 42u)
__device__ __forceinline__ void tf8(uint32_t (&x0)[8], uint32_t (&x1)[8]) {
#define R8(r) \
  { _Pragma("unroll") for (int j = 0; j < 8; ++j) { x0[j] += x1[j]; x1[j] = rotl(x1[j], r); x1[j] ^= x0[j]; } }
#define K8(a, b) \
  { _Pragma("unroll") for (int j = 0; j < 8; ++j) { x0[j] += (a); x1[j] += (b); } }
  K8(0u, TFK1)
  R8(13) R8(15) R8(26) R8(6)  K8(TFK1, TFK2 + 1u)
  R8(17) R8(29) R8(16) R8(24) K8(TFK2, 0u + 2u)
  R8(13) R8(15) R8(26) R8(6)  K8(0u, TFK1 + 3u)
  R8(17) R8(29) R8(16) R8(24) K8(TFK1, TFK2 + 4u)
  R8(13) R8(15) R8(26) R8(6)  K8(TFK2, 0u + 5u)
#undef R8
#undef K8
}

__device__ __forceinline__ float gumbel_from_bits(uint32_t bits) {
  float f = __uint_as_float((bits >> 9) | 0x3f800000u) - 1.0f;
  float u = fmaxf(f, 1.17549435e-38f);
  float t = __log2f(u);
  float s = __log2f(-t);
  return fmaf(0.69314718f, s, -0.36651292f);
}

// order-isomorphic u64 key: higher val wins; on equal val, LOWER idx wins
__device__ __forceinline__ unsigned long long pack_key(float val, int idx) {
  uint32_t fb = __float_as_uint(val);
  uint32_t key = (fb & 0x80000000u) ? ~fb : (fb | 0x80000000u);
  return ((unsigned long long)key << 32) |
         (unsigned long long)(0xFFFFFFFFu - (uint32_t)idx);
}

// ---------------- K1: LayerNorm + Q projection ----------------
__global__ __launch_bounds__(256, 4) void ln_qproj_kernel(
                                const float* __restrict__ queries,
                                const float* __restrict__ Wq,
                                const float* __restrict__ ln_g,
                                const float* __restrict__ ln_b,
                                float* __restrict__ q_ws) {
  __shared__ float xnT[QD][4];
  const int tid = threadIdx.x;
  const int wave = tid >> 6, lane = tid & 63;
  const int r0 = blockIdx.x * 4;
  const int r = r0 + wave;

  float vals[8];
  float s = 0.f;
#pragma unroll
  for (int j = 0; j < 8; ++j) { vals[j] = queries[r * QD + j * 64 + lane]; s += vals[j]; }
#pragma unroll
  for (int m = 32; m >= 1; m >>= 1) s += __shfl_xor(s, m, 64);
  const float mu = s * (1.f / 512.f);
  float ss = 0.f;
#pragma unroll
  for (int j = 0; j < 8; ++j) { float d = vals[j] - mu; ss += d * d; }
#pragma unroll
  for (int m = 32; m >= 1; m >>= 1) ss += __shfl_xor(ss, m, 64);
  const float rstd = 1.f / sqrtf(ss * (1.f / 512.f) + 1e-5f);
#pragma unroll
  for (int j = 0; j < 8; ++j) {
    int e = j * 64 + lane;
    xnT[e][wave] = (vals[j] - mu) * rstd * ln_g[e] + ln_b[e];
  }
  __syncthreads();

  const int e = blockIdx.y * 256 + tid;
  float a0 = 0.f, a1 = 0.f, a2 = 0.f, a3 = 0.f;
#pragma unroll 4
  for (int i = 0; i < QD; ++i) {
    f32x4 xv = *(const f32x4*)&xnT[i][0];
    float w = Wq[i * EMBD + e];
    a0 += xv.x * w; a1 += xv.y * w; a2 += xv.z * w; a3 += xv.w * w;
  }
  q_ws[(r0 + 0) * EMBD + e] = a0;
  q_ws[(r0 + 1) * EMBD + e] = a1;
  q_ws[(r0 + 2) * EMBD + e] = a2;
  q_ws[(r0 + 3) * EMBD + e] = a3;
}

// ---------------- K2: k = glove @ Wk (bitwise-identical pk path) ----------------
#define BKk 60
__global__ __launch_bounds__(256, 4) void kproj_kernel(
                             const float* __restrict__ glove,
                             const float* __restrict__ Wk,
                             float* __restrict__ k_ws) {
  __shared__ float AsT[BKk][68];
  __shared__ float Bs[BKk][64];
  const int tid = threadIdx.x;
  const int v0 = blockIdx.x * 64, n0 = blockIdx.y * 64;
  const int ty = tid >> 4, tx = tid & 15;
  f32x2 acc2[4][2] = {};
  for (int s = 0; s < 5; ++s) {
    const int w0 = s * BKk;
    __syncthreads();
    for (int f = tid; f < 64 * 15; f += 256) {
      int row = f / 15, c4 = f % 15;
      int v = v0 + row;
      float4 g4 = (v < VOCAB) ? *(const float4*)&glove[(size_t)v * WDn + w0 + c4 * 4]
                              : make_float4(0.f, 0.f, 0.f, 0.f);
      AsT[c4 * 4 + 0][row] = g4.x;
      AsT[c4 * 4 + 1][row] = g4.y;
      AsT[c4 * 4 + 2][row] = g4.z;
      AsT[c4 * 4 + 3][row] = g4.w;
    }
    for (int f = tid; f < BKk * 16; f += 256) {
      int row = f / 16, c4 = f % 16;
      *(float4*)&Bs[row][c4 * 4] = *(const float4*)&Wk[(size_t)(w0 + row) * EMBD + n0 + c4 * 4];
    }
    __syncthreads();
#pragma unroll 4
    for (int w = 0; w < BKk; ++w) {
      f32x4 aq = *(const f32x4*)&AsT[w][ty * 4];
      f32x4 bv = *(const f32x4*)&Bs[w][tx * 4];
      f32x2 bl = lo2(bv), bh = hi2(bv);
      f32x2 a01 = lo2(aq), a23 = hi2(aq);
      pk_fma_blo(acc2[0][0], a01, bl); pk_fma_blo(acc2[0][1], a01, bh);
      pk_fma_bhi(acc2[1][0], a01, bl); pk_fma_bhi(acc2[1][1], a01, bh);
      pk_fma_blo(acc2[2][0], a23, bl); pk_fma_blo(acc2[2][1], a23, bh);
      pk_fma_bhi(acc2[3][0], a23, bl); pk_fma_bhi(acc2[3][1], a23, bh);
    }
  }
#pragma unroll
  for (int i = 0; i < 4; ++i) {
    int v = v0 + ty * 4 + i;
    if (v < VOCAB) {
      float4 st = make_float4(acc2[i][0].x, acc2[i][0].y, acc2[i][1].x, acc2[i][1].y);
      *(float4*)&k_ws[(size_t)v * EMBD + n0 + tx * 4] = st;
    }
  }
}

// ---------------- K3: scores + gumbel + argmax via atomicMax ----------------
template<bool FULL>
__device__ __forceinline__ void score_epi(const f32x2 (&acc)[4][8],
                                          int v0, int tx, int ty, int rowtile, int h,
                                          unsigned long long* __restrict__ pk_buf) {
#pragma unroll
  for (int i = 0; i < 4; ++i) {
    const int r = rowtile * 64 + ty * 4 + i;
    const int b = r >> 7, q = r & 127;
    const int rowidx = (b * NH + h) * NQn + q;
    const uint32_t base = (uint32_t)rowidx * (uint32_t)VOCAB;

    uint32_t x0[8], x1[8];
#pragma unroll
    for (int j = 0; j < 8; ++j) {
      x0[j] = 0u;
      x1[j] = base + (uint32_t)(v0 + tx + 16 * j);
    }
    tf8(x0, x1);

    float best = -INFINITY; int bidx = 0x7fffffff;
#pragma unroll
    for (int j = 0; j < 8; ++j) {
      int v = v0 + tx + 16 * j;
      if (FULL || v < VOCAB) {
        float g = gumbel_from_bits(x0[j] ^ x1[j]);
        float val = (acc[i][j].x + acc[i][j].y) - g;  // q pre-scaled by 0.125
        if (val > best) { best = val; bidx = v; }     // v increasing -> lowest-idx ties
      }
    }
#pragma unroll
    for (int m = 8; m >= 1; m >>= 1) {
      float ov = __shfl_xor(best, m, 64);
      int   oi = __shfl_xor(bidx, m, 64);
      if (ov > best || (ov == best && oi < bidx)) { best = ov; bidx = oi; }
    }
    if (tx == 0) atomicMax(&pk_buf[rowidx], pack_key(best, bidx));
  }
}

// LDS 52 KB caps us at 3 blocks/CU; pin waves/EU max=3 so the allocator is
// free to use ~168 VGPRs and keep acc + k-tile staging resident (no LDS remat).
__global__ __attribute__((amdgpu_flat_work_group_size(256, 256),
                          amdgpu_waves_per_eu(3, 3)))
void score_kernel(const float* __restrict__ q_ws,
                  const float* __restrict__ k_ws,
                  unsigned long long* __restrict__ pk_buf) {
  __shared__ float Qs[64 * 68];
  __shared__ float Ks[128 * 68];
  const int tid = threadIdx.x;
  const int chunk = blockIdx.x, rowtile = blockIdx.y, h = blockIdx.z;
  const int v0 = chunk * VCHUNK;
  const int ty = tid >> 4, tx = tid & 15;

  for (int f = tid; f < 64 * 16; f += 256) {
    int row = f >> 4, c4 = f & 15;
    f32x4 qv = *(const f32x4*)&q_ws[(size_t)(rowtile * 64 + row) * EMBD + h * DHn + c4 * 4];
    qv *= 0.125f;                                    // fold scale (2^-3, exact)
    *(f32x4*)&Qs[row * 68 + c4 * 4] = qv;
  }
  for (int f = tid; f < 128 * 16; f += 256) {
    int row = f >> 4, c4 = f & 15;
    int v = v0 + row;
    f32x4 k4 = {0.f, 0.f, 0.f, 0.f};
    if (v < VOCAB) k4 = *(const f32x4*)&k_ws[(size_t)v * EMBD + h * DHn + c4 * 4];
    *(f32x4*)&Ks[row * 68 + c4 * 4] = k4;
  }
  __syncthreads();

  f32x2 acc[4][8] = {};
#pragma unroll 1
  for (int d0 = 0; d0 < DHn; d0 += 4) {
    const float* kb = &Ks[tx * 68 + d0];
    f32x4 k0 = *(const f32x4*)(kb + 0 * 16 * 68);
    f32x4 k1 = *(const f32x4*)(kb + 1 * 16 * 68);
    f32x4 k2 = *(const f32x4*)(kb + 2 * 16 * 68);
    f32x4 k3 = *(const f32x4*)(kb + 3 * 16 * 68);
    f32x4 k4 = *(const f32x4*)(kb + 4 * 16 * 68);
    f32x4 k5 = *(const f32x4*)(kb + 5 * 16 * 68);
    f32x4 k6 = *(const f32x4*)(kb + 6 * 16 * 68);
    f32x4 k7 = *(const f32x4*)(kb + 7 * 16 * 68);
#pragma unroll
    for (int i = 0; i < 4; ++i) {
      f32x4 qv = *(const f32x4*)&Qs[(ty * 4 + i) * 68 + d0];
      f32x2 ql = lo2(qv), qh = hi2(qv);
      pk_fma(acc[i][0], ql, lo2(k0)); pk_fma(acc[i][0], qh, hi2(k0));
      pk_fma(acc[i][1], ql, lo2(k1)); pk_fma(acc[i][1], qh, hi2(k1));
      pk_fma(acc[i][2], ql, lo2(k2)); pk_fma(acc[i][2], qh, hi2(k2));
      pk_fma(acc[i][3], ql, lo2(k3)); pk_fma(acc[i][3], qh, hi2(k3));
      pk_fma(acc[i][4], ql, lo2(k4)); pk_fma(acc[i][4], qh, hi2(k4));
      pk_fma(acc[i][5], ql, lo2(k5)); pk_fma(acc[i][5], qh, hi2(k5));
      pk_fma(acc[i][6], ql, lo2(k6)); pk_fma(acc[i][6], qh, hi2(k6));
      pk_fma(acc[i][7], ql, lo2(k7)); pk_fma(acc[i][7], qh, hi2(k7));
    }
  }

  if (v0 + VCHUNK <= VOCAB)
    score_epi<true>(acc, v0, tx, ty, rowtile, h, pk_buf);
  else
    score_epi<false>(acc, v0, tx, ty, rowtile, h, pk_buf);
}

// ---------------- K5: gather + V projection + out proj + residual ----------------
__global__ __launch_bounds__(256, 4) void out_kernel(
                           const float* __restrict__ queries,
                           const float* __restrict__ glove,
                           const float* __restrict__ Wv,
                           const float* __restrict__ Wout,
                           const float* __restrict__ b_out,
                           const unsigned long long* __restrict__ pk_buf,
                           float* __restrict__ out) {
  __shared__ float gl[4][NH][WDn];
  __shared__ float vrow[4][EMBD];
  __shared__ int idxs[4][NH];
  const int tid = threadIdx.x;
  const int r0 = blockIdx.x * 4;
  if (tid < 32) {
    int rr = tid >> 3, hh = tid & 7;
    int r = r0 + rr, b = r >> 7, q = r & 127;
    unsigned long long p = pk_buf[(b * NH + hh) * NQn + q];
    idxs[rr][hh] = (int)(0xFFFFFFFFu - (uint32_t)(p & 0xFFFFFFFFull));
  }
  __syncthreads();
  for (int f = tid; f < 32 * 75; f += 256) {
    int rp = f / 75, c4 = f % 75;
    int rr = rp >> 3, hh = rp & 7;
    *(float4*)&gl[rr][hh][c4 * 4] = *(const float4*)&glove[(size_t)idxs[rr][hh] * WDn + c4 * 4];
  }
  __syncthreads();
  for (int e = tid; e < EMBD; e += 256) {
    float a0 = 0.f, a1 = 0.f, a2 = 0.f, a3 = 0.f;
    int hh = e >> 6;
    for (int w = 0; w < WDn; ++w) {
      float wv = Wv[(size_t)w * EMBD + e];
      a0 += gl[0][hh][w] * wv; a1 += gl[1][hh][w] * wv;
      a2 += gl[2][hh][w] * wv; a3 += gl[3][hh][w] * wv;
    }
    vrow[0][e] = a0; vrow[1][e] = a1; vrow[2][e] = a2; vrow[3][e] = a3;
  }
  __syncthreads();
  for (int j = tid; j < EMBD; j += 256) {
    float a0 = 0.f, a1 = 0.f, a2 = 0.f, a3 = 0.f;
    for (int e = 0; e < EMBD; ++e) {
      float wo = Wout[(size_t)e * QD + j];
      a0 += vrow[0][e] * wo; a1 += vrow[1][e] * wo;
      a2 += vrow[2][e] * wo; a3 += vrow[3][e] * wo;
    }
    float bb = b_out[j];
    out[(size_t)(r0 + 0) * QD + j] = queries[(size_t)(r0 + 0) * QD + j] + a0 + bb;
    out[(size_t)(r0 + 1) * QD + j] = queries[(size_t)(r0 + 1) * QD + j] + a1 + bb;
    out[(size_t)(r0 + 2) * QD + j] = queries[(size_t)(r0 + 2) * QD + j] + a2 + bb;
    out[(size_t)(r0 + 3) * QD + j] = queries[(size_t)(r0 + 3) * QD + j] + a3 + bb;
  }
}

extern "C" void kernel_launch(void* const* d_in, const int* in_sizes, int n_in,
                              void* d_out, int out_size, void* d_ws, size_t ws_size,
                              hipStream_t stream) {
  const float* queries = (const float*)d_in[0];
  const float* glove   = (const float*)d_in[1];
  const float* Wq      = (const float*)d_in[2];
  const float* Wk      = (const float*)d_in[3];
  const float* Wv      = (const float*)d_in[4];
  const float* Wout    = (const float*)d_in[5];
  const float* b_out   = (const float*)d_in[6];
  const float* ln_g    = (const float*)d_in[7];
  const float* ln_b    = (const float*)d_in[8];
  float* out = (float*)d_out;

  float* ws   = (float*)d_ws;
  float* q_ws = ws;
  float* k_ws = q_ws + (size_t)NB * NQn * EMBD;
  unsigned long long* pk_buf =
      (unsigned long long*)(k_ws + (size_t)VOCAB * EMBD);

  hipMemsetAsync(pk_buf, 0, (size_t)NB * NH * NQn * sizeof(unsigned long long), stream);

  hipLaunchKernelGGL(ln_qproj_kernel, dim3(128, 2), dim3(256), 0, stream,
                     queries, Wq, ln_g, ln_b, q_ws);
  hipLaunchKernelGGL(kproj_kernel, dim3(313, 8), dim3(256), 0, stream,
                     glove, Wk, k_ws);
  hipLaunchKernelGGL(score_kernel, dim3(NCHUNK, 8, NH), dim3(256), 0, stream,
                     q_ws, k_ws, pk_buf);
  hipLaunchKernelGGL(out_kernel, dim3(128), dim3(256), 0, stream,
                     queries, glove, Wv, Wout, b_out, pk_buf, out);
}